// Round 3
// baseline (90.293 us; speedup 1.0000x reference)
//
#include <hip/hip_runtime.h>
#include <hip/hip_bf16.h>

#define B_ROWS 8192
#define E_DIM  1024
#define MARGIN 0.2f

#define BM 128
#define BN 128
#define BK 32
#define KSPLIT 2
#define KHALF (E_DIM / KSPLIT)     // 512
#define NSTEPS (KHALF / BK)        // 16
#define APAD 40                    // As row stride in bf16 (80 B: spreads all 8 bank-quads)

typedef __bf16 bf16x8 __attribute__((ext_vector_type(8)));
typedef float  f32x4  __attribute__((ext_vector_type(4)));

__device__ __forceinline__ void gload_lds16(const void* g, void* l) {
    __builtin_amdgcn_global_load_lds(
        (__attribute__((address_space(1))) void*)(g),
        (__attribute__((address_space(3))) void*)(l),
        16, 0, 0);
}

// Wt[n][e] = bf16(W[e][n]) -- GEMM B-operand contiguous along K(=e)
__global__ void transpose_w(const float* __restrict__ W, __bf16* __restrict__ Wt) {
    __shared__ __bf16 tile[32][33];
    int tx = threadIdx.x, ty = threadIdx.y;
    int bx = blockIdx.x * 32;   // n base
    int by = blockIdx.y * 32;   // e base
    tile[ty][tx] = (__bf16)W[(size_t)(by + ty) * E_DIM + bx + tx];
    __syncthreads();
    Wt[(size_t)(bx + ty) * E_DIM + by + tx] = tile[tx][ty];
}

// Fused GEMM: u = (0.4*m + 0.6*tr_m) @ Wt^T, epilogue dot with (A_is - A_em),
// atomicAdd partial sums into delta[]. 128x128 tile, BK=32, split-K=2,
// A reg-staged (combine on the fly) into padded LDS, B via global_load_lds,
// 2-phase double-buffered, one barrier per K-step.
__global__ __launch_bounds__(256)
void gemm_fused(const float* __restrict__ mIn, const float* __restrict__ trmIn,
                const __bf16* __restrict__ Wt,
                const float* __restrict__ Ais, const float* __restrict__ Aem,
                float* __restrict__ delta) {
    __shared__ __bf16 As[2][BM * APAD];   // 2 x 10 KiB (padded, reg-staged)
    __shared__ __bf16 Bs[2][BN * BK];     // 2 x  8 KiB (linear, global_load_lds)

    const int tid  = threadIdx.x;
    const int lane = tid & 63;
    const int wave = tid >> 6;
    const int lr   = lane & 15;
    const int hi   = lane >> 4;
    const int wr   = wave >> 1, wc = wave & 1;

    // Bijective XCD swizzle: 1024 blocks = 8 xcd x (16 groups x 8 colblocks).
    // 8 col-blocks of one (panel,khalf) group share one XCD -> A-rows L2-hit.
    const int bid = blockIdx.x;
    const int xcd = bid & 7;
    const int j   = bid >> 3;        // 0..127
    const int col = j & 7;
    const int gw  = j >> 3;          // 0..15
    const int grp = xcd * 16 + gw;   // 0..127
    const int rb     = (grp >> 1) * BM;
    const int k_base = (grp & 1) * KHALF;
    const int cb     = col * BN;

    // A staging: thread t covers row = t>>1, 16 floats at kof = (t&1)*16
    const int arow = tid >> 1;
    const int akof = (tid & 1) * 16;
    const float* pm = mIn   + (size_t)(rb + arow) * E_DIM + k_base + akof;
    const float* pt = trmIn + (size_t)(rb + arow) * E_DIM + k_base + akof;
    __bf16* asdst0 = &As[0][arow * APAD + akof];
    __bf16* asdst1 = &As[1][arow * APAD + akof];

    auto issueB = [&](int buf, int k0) {
#pragma unroll
        for (int i = 0; i < 2; ++i) {
            int o    = i * 4096 + wave * 1024 + lane * 16;  // byte in 8 KiB tile
            int bcol = o >> 6;                              // 64 B per 32-bf16 row
            int kb   = o & 63;
            gload_lds16((const char*)Wt + ((size_t)(cb + bcol) * E_DIM + k0) * 2 + kb,
                        (char*)(&Bs[buf][0]) + i * 4096 + wave * 1024);
        }
    };

    auto combineWrite = [&](__bf16* dst,
                            const float4& m0, const float4& m1, const float4& m2, const float4& m3,
                            const float4& t0, const float4& t1, const float4& t2, const float4& t3) {
        bf16x8 v0, v1;
        v0[0] = (__bf16)(0.4f*m0.x + 0.6f*t0.x); v0[1] = (__bf16)(0.4f*m0.y + 0.6f*t0.y);
        v0[2] = (__bf16)(0.4f*m0.z + 0.6f*t0.z); v0[3] = (__bf16)(0.4f*m0.w + 0.6f*t0.w);
        v0[4] = (__bf16)(0.4f*m1.x + 0.6f*t1.x); v0[5] = (__bf16)(0.4f*m1.y + 0.6f*t1.y);
        v0[6] = (__bf16)(0.4f*m1.z + 0.6f*t1.z); v0[7] = (__bf16)(0.4f*m1.w + 0.6f*t1.w);
        v1[0] = (__bf16)(0.4f*m2.x + 0.6f*t2.x); v1[1] = (__bf16)(0.4f*m2.y + 0.6f*t2.y);
        v1[2] = (__bf16)(0.4f*m2.z + 0.6f*t2.z); v1[3] = (__bf16)(0.4f*m2.w + 0.6f*t2.w);
        v1[4] = (__bf16)(0.4f*m3.x + 0.6f*t3.x); v1[5] = (__bf16)(0.4f*m3.y + 0.6f*t3.y);
        v1[6] = (__bf16)(0.4f*m3.z + 0.6f*t3.z); v1[7] = (__bf16)(0.4f*m3.w + 0.6f*t3.w);
        *(bf16x8*)(dst)     = v0;
        *(bf16x8*)(dst + 8) = v1;
    };

    f32x4 acc[4][4] = {};

    // ---- prologue: stage step 0 into buf 0
    {
        float4 m0 = *(const float4*)(pm),     m1 = *(const float4*)(pm + 4);
        float4 m2 = *(const float4*)(pm + 8), m3 = *(const float4*)(pm + 12);
        float4 t0 = *(const float4*)(pt),     t1 = *(const float4*)(pt + 4);
        float4 t2 = *(const float4*)(pt + 8), t3 = *(const float4*)(pt + 12);
        issueB(0, k_base);
        combineWrite(asdst0, m0, m1, m2, m3, t0, t1, t2, t3);
    }
    __syncthreads();

    int cur = 0;
    for (int t = 0; t < NSTEPS; ++t) {
        const int nxt = cur ^ 1;
        const bool pf = (t + 1) < NSTEPS;

        // ---- issue next-step loads FIRST (A regs held across MFMA; B in LDS queue)
        float4 m0, m1, m2, m3, t0, t1, t2, t3;
        if (pf) {
            const int ko = (t + 1) * BK;
            m0 = *(const float4*)(pm + ko);      m1 = *(const float4*)(pm + ko + 4);
            m2 = *(const float4*)(pm + ko + 8);  m3 = *(const float4*)(pm + ko + 12);
            t0 = *(const float4*)(pt + ko);      t1 = *(const float4*)(pt + ko + 4);
            t2 = *(const float4*)(pt + ko + 8);  t3 = *(const float4*)(pt + ko + 12);
            issueB(nxt, k_base + ko);
        }

        // ---- compute current tile
        bf16x8 a[4], b[4];
#pragma unroll
        for (int mi = 0; mi < 4; ++mi)
            a[mi] = *(const bf16x8*)(&As[cur][(wr * 64 + mi * 16 + lr) * APAD + hi * 8]);
#pragma unroll
        for (int ni = 0; ni < 4; ++ni)
            b[ni] = *(const bf16x8*)(&Bs[cur][(wc * 64 + ni * 16 + lr) * BK + hi * 8]);
#pragma unroll
        for (int mi = 0; mi < 4; ++mi)
#pragma unroll
            for (int ni = 0; ni < 4; ++ni)
                acc[mi][ni] = __builtin_amdgcn_mfma_f32_16x16x32_bf16(
                    a[mi], b[ni], acc[mi][ni], 0, 0, 0);

        // ---- land next A tile (waits only the float4s: vmcnt leaves B in flight)
        if (pf)
            combineWrite((nxt == 0) ? asdst0 : asdst1, m0, m1, m2, m3, t0, t1, t2, t3);
        __syncthreads();
        cur = nxt;
    }

    // ---- epilogue: delta[r] += sum_col u[r][col] * (Ais - Aem)[r][col]
    // C/D layout: col = lane&15, row = (lane>>4)*4 + reg
    const int colbase = cb + wc * 64 + lr;
    const int rowbase = rb + wr * 64 + hi * 4;
#pragma unroll
    for (int mi = 0; mi < 4; ++mi) {
#pragma unroll
        for (int jj = 0; jj < 4; ++jj) {
            int r = rowbase + mi * 16 + jj;
            float v = 0.f;
#pragma unroll
            for (int ni = 0; ni < 4; ++ni) {
                size_t idx = (size_t)r * E_DIM + colbase + ni * 16;
                v += acc[mi][ni][jj] * (Ais[idx] - Aem[idx]);
            }
            v += __shfl_xor(v, 1);
            v += __shfl_xor(v, 2);
            v += __shfl_xor(v, 4);
            v += __shfl_xor(v, 8);
            if (lr == 0) atomicAdd(&delta[r], v);
        }
    }
}

__global__ void hinge_sum(const float* __restrict__ delta, float* __restrict__ out) {
    float s = 0.f;
    for (int i = threadIdx.x; i < B_ROWS; i += 256)
        s += fmaxf(MARGIN + delta[i], 0.f);
#pragma unroll
    for (int off = 32; off > 0; off >>= 1) s += __shfl_down(s, off);
    __shared__ float wsum[4];
    int lane = threadIdx.x & 63, w = threadIdx.x >> 6;
    if (lane == 0) wsum[w] = s;
    __syncthreads();
    if (threadIdx.x == 0) out[0] = wsum[0] + wsum[1] + wsum[2] + wsum[3];
}

extern "C" void kernel_launch(void* const* d_in, const int* in_sizes, int n_in,
                              void* d_out, int out_size, void* d_ws, size_t ws_size,
                              hipStream_t stream) {
    const float* A_is = (const float*)d_in[0];
    const float* A_em = (const float*)d_in[1];
    const float* m    = (const float*)d_in[2];
    const float* tr_m = (const float*)d_in[3];
    const float* W    = (const float*)d_in[4];
    // d_in[5] = b : cancels in diag_is - diag_em, unused.
    float* out = (float*)d_out;

    char* ws = (char*)d_ws;
    __bf16* wt    = (__bf16*)ws;                             // 2 MiB
    float*  delta = (float*)(ws + (size_t)2 * 1024 * 1024);  // 32 KiB

    hipMemsetAsync(delta, 0, B_ROWS * sizeof(float), stream);
    transpose_w<<<dim3(32, 32), dim3(32, 32), 0, stream>>>(W, wt);
    gemm_fused<<<1024, 256, 0, stream>>>(m, tr_m, wt, A_is, A_em, delta);
    hinge_sum<<<1, 256, 0, stream>>>(delta, out);
}

// Round 4
// 66.211 us; speedup vs baseline: 1.3637x; 1.3637x over previous
//
#include <hip/hip_runtime.h>
#include <hip/hip_bf16.h>

#define B_ROWS 8192
#define E_DIM  1024
#define MARGIN 0.2f

#define BM 128
#define BN 128
#define BK 32
#define KSPLIT 2
#define KHALF (E_DIM / KSPLIT)   // 512
#define NSTEPS (KHALF / BK)      // 16

typedef __bf16 bf16x8 __attribute__((ext_vector_type(8)));
typedef float  f32x4  __attribute__((ext_vector_type(4)));

__device__ __forceinline__ void gload_lds16(const void* g, void* l) {
    __builtin_amdgcn_global_load_lds(
        (__attribute__((address_space(1))) void*)(g),
        (__attribute__((address_space(3))) void*)(l),
        16, 0, 0);
}

// c = 0.4*m + 0.6*tr_m, fp32 -> bf16, 8 elems/thread (proven ~13 us, BW-bound)
__global__ void prep_c(const float* __restrict__ m, const float* __restrict__ trm,
                       __bf16* __restrict__ c) {
    size_t i = ((size_t)blockIdx.x * blockDim.x + threadIdx.x) * 8;
    float4 m0 = *(const float4*)(m + i);
    float4 m1 = *(const float4*)(m + i + 4);
    float4 t0 = *(const float4*)(trm + i);
    float4 t1 = *(const float4*)(trm + i + 4);
    bf16x8 v;
    v[0] = (__bf16)(0.4f*m0.x + 0.6f*t0.x);
    v[1] = (__bf16)(0.4f*m0.y + 0.6f*t0.y);
    v[2] = (__bf16)(0.4f*m0.z + 0.6f*t0.z);
    v[3] = (__bf16)(0.4f*m0.w + 0.6f*t0.w);
    v[4] = (__bf16)(0.4f*m1.x + 0.6f*t1.x);
    v[5] = (__bf16)(0.4f*m1.y + 0.6f*t1.y);
    v[6] = (__bf16)(0.4f*m1.z + 0.6f*t1.z);
    v[7] = (__bf16)(0.4f*m1.w + 0.6f*t1.w);
    *(bf16x8*)(c + i) = v;
}

// Wt[n][e] = bf16(W[e][n]) -- GEMM B-operand contiguous along K(=e)
__global__ void transpose_w(const float* __restrict__ W, __bf16* __restrict__ Wt) {
    __shared__ __bf16 tile[32][33];
    int tx = threadIdx.x, ty = threadIdx.y;
    int bx = blockIdx.x * 32;   // n base
    int by = blockIdx.y * 32;   // e base
    tile[ty][tx] = (__bf16)W[(size_t)(by + ty) * E_DIM + bx + tx];
    __syncthreads();
    Wt[(size_t)(bx + ty) * E_DIM + by + tx] = tile[tx][ty];
}

// u = c @ Wt^T with T3-minimum 2-phase pipeline: BOTH operands staged via
// global_load_lds (cannot be compiler-sunk), prefetch issued BEFORE compute,
// ONE barrier per K-step. 128x128 tile, BK=32, split-K=2 -> 1024 blocks.
// Epilogue: rowwise dot with (A_is - A_em), atomicAdd into delta[].
__global__ __launch_bounds__(256)
void gemm_dot(const __bf16* __restrict__ Cm, const __bf16* __restrict__ Wt,
              const float* __restrict__ Ais, const float* __restrict__ Aem,
              float* __restrict__ delta) {
    __shared__ __bf16 As[2][BM * BK];   // 2 x 8 KiB, linear
    __shared__ __bf16 Bs[2][BN * BK];   // 2 x 8 KiB, linear

    const int tid  = threadIdx.x;
    const int lane = tid & 63;
    const int wave = tid >> 6;
    const int lr   = lane & 15;
    const int hi   = lane >> 4;
    const int wr   = wave >> 1, wc = wave & 1;

    // XCD swizzle: 1024 blocks = 8 xcd x (16 groups x 8 colblocks).
    // The 8 col-blocks of one (panel,khalf) group land on one XCD ->
    // c-panel (128 KiB) is HBM-read once, L2-hit 7x.
    const int bid = blockIdx.x;
    const int xcd = bid & 7;
    const int l   = bid >> 3;          // 0..127
    const int col = l & 7;
    const int gw  = l >> 3;            // 0..15
    const int grp = xcd * 16 + gw;     // 0..127
    const int rb     = (grp >> 1) * BM;
    const int kbase  = (grp & 1) * KHALF;
    const int cb     = col * BN;

    auto stage = [&](int buf, int k0) {
#pragma unroll
        for (int i = 0; i < 2; ++i) {
            int off = i * 4096 + tid * 16;   // byte offset in 8 KiB tile
            int row = off >> 6;              // 64 B per 32-bf16 row
            int kb  = off & 63;
            gload_lds16((const char*)Cm + ((size_t)(rb + row) * E_DIM + k0) * 2 + kb,
                        (char*)(&As[buf][0]) + off);
            gload_lds16((const char*)Wt + ((size_t)(cb + row) * E_DIM + k0) * 2 + kb,
                        (char*)(&Bs[buf][0]) + off);
        }
    };

    f32x4 acc[4][4] = {};

    // prologue
    stage(0, kbase);
    __syncthreads();

    int cur = 0;
    for (int t = 0; t < NSTEPS; ++t) {
        // issue next-tile loads FIRST -- global_load_lds is fire-and-forget,
        // stays in flight across the whole compute phase below
        if (t + 1 < NSTEPS) stage(cur ^ 1, kbase + (t + 1) * BK);

        bf16x8 a[4], b[4];
#pragma unroll
        for (int mi = 0; mi < 4; ++mi)
            a[mi] = *(const bf16x8*)(&As[cur][(wr * 64 + mi * 16 + lr) * BK + hi * 8]);
#pragma unroll
        for (int ni = 0; ni < 4; ++ni)
            b[ni] = *(const bf16x8*)(&Bs[cur][(wc * 64 + ni * 16 + lr) * BK + hi * 8]);

#pragma unroll
        for (int mi = 0; mi < 4; ++mi)
#pragma unroll
            for (int ni = 0; ni < 4; ++ni)
                acc[mi][ni] = __builtin_amdgcn_mfma_f32_16x16x32_bf16(
                    a[mi], b[ni], acc[mi][ni], 0, 0, 0);

        __syncthreads();   // single barrier/K-step (drains vmcnt -> nxt ready)
        cur ^= 1;
    }

    // epilogue: delta[r] += sum_col u[r][col] * (Ais - Aem)[r][col]
    // C/D layout (16x16x32): col = lane&15, row = (lane>>4)*4 + reg
    const int colbase = cb + wc * 64 + lr;
    const int rowbase = rb + wr * 64 + hi * 4;
#pragma unroll
    for (int mi = 0; mi < 4; ++mi) {
#pragma unroll
        for (int jj = 0; jj < 4; ++jj) {
            int r = rowbase + mi * 16 + jj;
            float v = 0.f;
#pragma unroll
            for (int ni = 0; ni < 4; ++ni) {
                size_t idx = (size_t)r * E_DIM + colbase + ni * 16;
                v += acc[mi][ni][jj] * (Ais[idx] - Aem[idx]);
            }
            v += __shfl_xor(v, 1);
            v += __shfl_xor(v, 2);
            v += __shfl_xor(v, 4);
            v += __shfl_xor(v, 8);
            if (lr == 0) atomicAdd(&delta[r], v);
        }
    }
}

__global__ void hinge_sum(const float* __restrict__ delta, float* __restrict__ out) {
    float s = 0.f;
    for (int i = threadIdx.x; i < B_ROWS; i += 256)
        s += fmaxf(MARGIN + delta[i], 0.f);
#pragma unroll
    for (int off = 32; off > 0; off >>= 1) s += __shfl_down(s, off);
    __shared__ float wsum[4];
    int lane = threadIdx.x & 63, w = threadIdx.x >> 6;
    if (lane == 0) wsum[w] = s;
    __syncthreads();
    if (threadIdx.x == 0) out[0] = wsum[0] + wsum[1] + wsum[2] + wsum[3];
}

extern "C" void kernel_launch(void* const* d_in, const int* in_sizes, int n_in,
                              void* d_out, int out_size, void* d_ws, size_t ws_size,
                              hipStream_t stream) {
    const float* A_is = (const float*)d_in[0];
    const float* A_em = (const float*)d_in[1];
    const float* m    = (const float*)d_in[2];
    const float* tr_m = (const float*)d_in[3];
    const float* W    = (const float*)d_in[4];
    // d_in[5] = b : cancels in diag_is - diag_em, unused.
    float* out = (float*)d_out;

    char* ws = (char*)d_ws;
    __bf16* c     = (__bf16*)ws;                              // 16 MiB
    __bf16* wt    = (__bf16*)(ws + (size_t)16 * 1024 * 1024); //  2 MiB
    float*  delta = (float*) (ws + (size_t)18 * 1024 * 1024); // 32 KiB

    hipMemsetAsync(delta, 0, B_ROWS * sizeof(float), stream);
    prep_c<<<4096, 256, 0, stream>>>(m, tr_m, c);
    transpose_w<<<dim3(32, 32), dim3(32, 32), 0, stream>>>(W, wt);
    gemm_dot<<<1024, 256, 0, stream>>>(c, wt, A_is, A_em, delta);
    hinge_sum<<<1, 256, 0, stream>>>(delta, out);
}

// Round 5
// 65.143 us; speedup vs baseline: 1.3861x; 1.0164x over previous
//
#include <hip/hip_runtime.h>
#include <hip/hip_bf16.h>

#define B_ROWS 8192
#define E_DIM  1024
#define MARGIN 0.2f

#define BM 256
#define BN 256
#define BK 64
#define KSPLIT 2
#define KHALF (E_DIM / KSPLIT)   // 512
#define NT (KHALF / BK)          // 8 K-tiles per block

typedef __bf16 bf16x8 __attribute__((ext_vector_type(8)));
typedef float  f32x4  __attribute__((ext_vector_type(4)));

__device__ __forceinline__ void gload_lds16(const void* g, void* l) {
    __builtin_amdgcn_global_load_lds(
        (__attribute__((address_space(1))) void*)(g),
        (__attribute__((address_space(3))) void*)(l),
        16, 0, 0);
}

// c = 0.4*m + 0.6*tr_m, fp32 -> bf16 (BW-bound, ~13 us)
__global__ void prep_c(const float* __restrict__ m, const float* __restrict__ trm,
                       __bf16* __restrict__ c) {
    size_t i = ((size_t)blockIdx.x * blockDim.x + threadIdx.x) * 8;
    float4 m0 = *(const float4*)(m + i);
    float4 m1 = *(const float4*)(m + i + 4);
    float4 t0 = *(const float4*)(trm + i);
    float4 t1 = *(const float4*)(trm + i + 4);
    bf16x8 v;
    v[0] = (__bf16)(0.4f*m0.x + 0.6f*t0.x);
    v[1] = (__bf16)(0.4f*m0.y + 0.6f*t0.y);
    v[2] = (__bf16)(0.4f*m0.z + 0.6f*t0.z);
    v[3] = (__bf16)(0.4f*m0.w + 0.6f*t0.w);
    v[4] = (__bf16)(0.4f*m1.x + 0.6f*t1.x);
    v[5] = (__bf16)(0.4f*m1.y + 0.6f*t1.y);
    v[6] = (__bf16)(0.4f*m1.z + 0.6f*t1.z);
    v[7] = (__bf16)(0.4f*m1.w + 0.6f*t1.w);
    *(bf16x8*)(c + i) = v;
}

// Wt[n][e] = bf16(W[e][n]) -- GEMM B-operand contiguous along K(=e)
__global__ void transpose_w(const float* __restrict__ W, __bf16* __restrict__ Wt) {
    __shared__ __bf16 tile[32][33];
    int tx = threadIdx.x, ty = threadIdx.y;
    int bx = blockIdx.x * 32;
    int by = blockIdx.y * 32;
    tile[ty][tx] = (__bf16)W[(size_t)(by + ty) * E_DIM + bx + tx];
    __syncthreads();
    Wt[(size_t)(bx + ty) * E_DIM + by + tx] = tile[tx][ty];
}

// 256x256 tile, BK=64, 8 waves (2M x 4N), per-wave out 128x64.
// Per K-tile: all frags LDS->reg up front (one barrier/K-tile), then stage
// tile t+2 (race-free: buffer fully consumed), then 64-MFMA cluster.
// Every stage load gets ~1 K-tile of flight before the barrier drain.
// T2 swizzle: LDS content pre-swizzled via global source addr (rule #21),
// reads XOR the same pattern: byte ^= ((row&7)<<4).
__global__ __launch_bounds__(512, 2)
void gemm_dot(const __bf16* __restrict__ Cm, const __bf16* __restrict__ Wt,
              const float* __restrict__ Ais, const float* __restrict__ Aem,
              float* __restrict__ delta) {
    __shared__ __bf16 Al[2][2][128 * 64];  // [dbuf][half][row128 x k64], 64 KiB
    __shared__ __bf16 Bl[2][2][128 * 64];  // 64 KiB

    const int tid  = threadIdx.x;
    const int lane = tid & 63;
    const int lr   = lane & 15;
    const int hi   = lane >> 4;
    const int wave = tid >> 6;     // 0..7
    const int wr   = wave >> 2;    // 0..1 : M half
    const int wc   = wave & 3;     // 0..3 : N quarter

    // 256 blocks = 8 xcd x 32. XCD x owns row-panels [4x..4x+3], all (colb,ks)
    // -> per-XCD L2 working set ~4 MiB (c panels + Wt), high L2 hit.
    const int bid  = blockIdx.x;
    const int xcd  = bid & 7;
    const int j    = bid >> 3;                 // 0..31
    const int sub  = j & 7;                    // 0..7
    const int rb    = (xcd * 4 + (j >> 3)) * BM;
    const int cbN   = (sub & 3) * BN;
    const int kbase = (sub >> 2) * KHALF;

    auto stage = [&](int buf, int t) {
        const int k0 = kbase + t * BK;
#pragma unroll
        for (int h = 0; h < 2; ++h) {
#pragma unroll
            for (int i = 0; i < 2; ++i) {
                const int d   = (i * 512 + tid) * 16;          // byte in 16 KiB half
                const int row = d >> 7;                        // 128 B per 64-bf16 row
                const int scb = (d & 127) ^ ((row & 7) << 4);  // inverse-swizzled source
                gload_lds16((const char*)Cm + ((size_t)(rb + h * 128 + row) * E_DIM + k0) * 2 + scb,
                            (char*)(&Al[buf][h][0]) + d);
                gload_lds16((const char*)Wt + ((size_t)(cbN + h * 128 + row) * E_DIM + k0) * 2 + scb,
                            (char*)(&Bl[buf][h][0]) + d);
            }
        }
    };

    f32x4 acc[8][4] = {};

    // prologue: stage tiles 0,1; one full drain
    stage(0, 0);
    stage(1, 1);
    __syncthreads();

    for (int t = 0; t < NT; ++t) {
        const int buf = t & 1;
        const char* Ab = (const char*)&Al[buf][wr][0];
        const char* Bb = (const char*)&Bl[buf][wc >> 1][0];

        // LDS -> regs: entire K-tile fragment set (24 x ds_read_b128)
        bf16x8 a[8][2], b[4][2];
#pragma unroll
        for (int mi = 0; mi < 8; ++mi) {
            const int row = mi * 16 + lr;
#pragma unroll
            for (int kk = 0; kk < 2; ++kk)
                a[mi][kk] = *(const bf16x8*)(Ab + row * 128 +
                              ((kk * 64 + hi * 16) ^ ((row & 7) << 4)));
        }
#pragma unroll
        for (int ni = 0; ni < 4; ++ni) {
            const int row = (wc & 1) * 64 + ni * 16 + lr;
#pragma unroll
            for (int kk = 0; kk < 2; ++kk)
                b[ni][kk] = *(const bf16x8*)(Bb + row * 128 +
                              ((kk * 64 + hi * 16) ^ ((row & 7) << 4)));
        }

        // all waves' reads done (lgkm+vm drained) -> buf reusable;
        // also drains own stage(t+1) loads (issued one full K-tile ago)
        __syncthreads();

        // issue tile t+2 into the buffer just freed; flies across MFMA(t)+reads(t+1)
        if (t + 2 < NT) stage(buf, t + 2);

        __builtin_amdgcn_s_setprio(1);
#pragma unroll
        for (int kk = 0; kk < 2; ++kk)
#pragma unroll
            for (int mi = 0; mi < 8; ++mi)
#pragma unroll
                for (int ni = 0; ni < 4; ++ni)
                    acc[mi][ni] = __builtin_amdgcn_mfma_f32_16x16x32_bf16(
                        a[mi][kk], b[ni][kk], acc[mi][ni], 0, 0, 0);
        __builtin_amdgcn_s_setprio(0);
    }

    // epilogue: delta[r] += sum_col u[r][col] * (Ais - Aem)[r][col]
    // C/D layout: col = lane&15, row = (lane>>4)*4 + reg
    const int colbase = cbN + wc * 64 + lr;
    const int rowb    = rb + wr * 128 + hi * 4;
#pragma unroll
    for (int mi = 0; mi < 8; ++mi) {
#pragma unroll
        for (int jj = 0; jj < 4; ++jj) {
            const int r = rowb + mi * 16 + jj;
            float v = 0.f;
#pragma unroll
            for (int ni = 0; ni < 4; ++ni) {
                const size_t idx = (size_t)r * E_DIM + colbase + ni * 16;
                v += acc[mi][ni][jj] * (Ais[idx] - Aem[idx]);
            }
            v += __shfl_xor(v, 1);
            v += __shfl_xor(v, 2);
            v += __shfl_xor(v, 4);
            v += __shfl_xor(v, 8);
            if (lr == 0) atomicAdd(&delta[r], v);
        }
    }
}

__global__ void hinge_sum(const float* __restrict__ delta, float* __restrict__ out) {
    float s = 0.f;
    for (int i = threadIdx.x; i < B_ROWS; i += 256)
        s += fmaxf(MARGIN + delta[i], 0.f);
#pragma unroll
    for (int off = 32; off > 0; off >>= 1) s += __shfl_down(s, off);
    __shared__ float wsum[4];
    int lane = threadIdx.x & 63, w = threadIdx.x >> 6;
    if (lane == 0) wsum[w] = s;
    __syncthreads();
    if (threadIdx.x == 0) out[0] = wsum[0] + wsum[1] + wsum[2] + wsum[3];
}

extern "C" void kernel_launch(void* const* d_in, const int* in_sizes, int n_in,
                              void* d_out, int out_size, void* d_ws, size_t ws_size,
                              hipStream_t stream) {
    const float* A_is = (const float*)d_in[0];
    const float* A_em = (const float*)d_in[1];
    const float* m    = (const float*)d_in[2];
    const float* tr_m = (const float*)d_in[3];
    const float* W    = (const float*)d_in[4];
    // d_in[5] = b : cancels in diag_is - diag_em, unused.
    float* out = (float*)d_out;

    char* ws = (char*)d_ws;
    __bf16* c     = (__bf16*)ws;                              // 16 MiB
    __bf16* wt    = (__bf16*)(ws + (size_t)16 * 1024 * 1024); //  2 MiB
    float*  delta = (float*) (ws + (size_t)18 * 1024 * 1024); // 32 KiB

    hipMemsetAsync(delta, 0, B_ROWS * sizeof(float), stream);
    prep_c<<<4096, 256, 0, stream>>>(m, tr_m, c);
    transpose_w<<<dim3(32, 32), dim3(32, 32), 0, stream>>>(W, wt);
    gemm_dot<<<256, 512, 0, stream>>>(c, wt, A_is, A_em, delta);
    hinge_sum<<<1, 256, 0, stream>>>(delta, out);
}